// Round 6
// baseline (269.778 us; speedup 1.0000x reference)
//
#include <hip/hip_runtime.h>

#define NEG_SLOPE 0.2f
#define RSHIFT 5       // range width 32 dst nodes -> LDS-resident counting sort
#define RW     32
#define MAXNR  1600    // supports N <= 51200
#define CHUNKP 8192    // edges per partition block (4096 caused pairs RMW bloat)

__device__ __forceinline__ ushort f2bf(float f) {
    union { float f; unsigned u; } c; c.f = f;
    unsigned u = c.u;
    return (ushort)((u + 0x7fffu + ((u >> 16) & 1u)) >> 16);   // RNE
}
__device__ __forceinline__ float bflo(unsigned u) { return __uint_as_float(u << 16); }
__device__ __forceinline__ float bfhi(unsigned u) { return __uint_as_float(u & 0xffff0000u); }

// ---------------- mega: partition FIRST (overlaps under scores), then fused
// scores+copy+convert. Weight rows padded to 132 floats (float4-aligned,
// 2-way-bank = free) so the dot loop is pure ds_read_b128.
__global__ __launch_bounds__(256) void mega_kernel(
    const float* __restrict__ x, const float* __restrict__ wu,
    const float* __restrict__ bu, const float* __restrict__ wv,
    const int* __restrict__ s0, const int* __restrict__ d0,
    const int* __restrict__ s1, const int* __restrict__ d1,
    float* __restrict__ out, ushort* __restrict__ xbf,
    float* __restrict__ su, float* __restrict__ sv,
    int* __restrict__ gcur, unsigned* __restrict__ pairs,
    int N, int E, int nr, int cap, int scoreBlocks, int ppset)
{
    __shared__ __align__(16) float smemf[32 * 132 + 16 * 132];  // 25.3 KB
    int* smi = (int*)smemf;                   // role C alias (needs 3*MAXNR=4800)
    float* wlds = smemf;                      // weights 32x132 (pad 132: f4-aligned)
    float* xtile = smemf + 32 * 132;          // x rows  16x132
    int tid = threadIdx.x;
    int bid = blockIdx.x;

    if (bid < 2 * ppset) {                    // ---- role C: partition edges
        int pb = bid;
        int t = pb / ppset, c = pb % ppset;
        const int* ss = t ? s1 : s0;
        const int* dd = t ? d1 : d0;
        int beg = c * CHUNKP, end = min(E, beg + CHUNKP);
        int* lcnt = smi; int* gb = smi + MAXNR; int* lrun = smi + 2 * MAXNR;
        for (int i = tid; i < nr; i += 256) lcnt[i] = 0;
        __syncthreads();
        for (int e = beg + tid; e < end; e += 256)
            atomicAdd(&lcnt[dd[e] >> RSHIFT], 1);
        __syncthreads();
        for (int i = tid; i < nr; i += 256) {
            gb[i] = atomicAdd(&gcur[t * nr + i], lcnt[i]);
            lrun[i] = 0;
        }
        __syncthreads();
        unsigned* pt = pairs + (size_t)t * nr * cap;
        for (int e = beg + tid; e < end; e += 256) {
            int dst = dd[e], src = ss[e];
            int rr = dst >> RSHIFT;
            int pos = atomicAdd(&lrun[rr], 1);
            pt[(size_t)rr * cap + gb[rr] + pos] = ((unsigned)dst << 16) | (unsigned)src;
        }
        return;
    }
    // ---- role B (fused): stage 16 rows + emit out/xbf, then scores from LDS
    int nb = bid - 2 * ppset;                 // 0..scoreBlocks-1
    int base = nb * 16;
    for (int i = tid; i < 1024; i += 256) {   // weights via float4: 32 rows x 32 f4
        int o = i >> 5, k4 = i & 31;
        float4 w = (o < 16) ? ((const float4*)wu)[i] : ((const float4*)wv)[i - 512];
        *(float4*)(wlds + o * 132 + k4 * 4) = w;
    }
    for (int i2 = tid; i2 < 512; i2 += 256) { // 16 rows x 32 float4
        int I = nb * 512 + i2;                // global float4 index into x
        int nl = i2 >> 5, q = i2 & 31;
        int n = base + nl;
        float4 v = make_float4(0.f, 0.f, 0.f, 0.f);
        if (n < N) {
            v = ((const float4*)x)[I];
            ((float4*)out)[(size_t)n * 96 + q] = v;
            ushort4 b;
            b.x = f2bf(v.x); b.y = f2bf(v.y); b.z = f2bf(v.z); b.w = f2bf(v.w);
            *(ushort4*)(xbf + (size_t)I * 4) = b;
        }
        ((float4*)(xtile + nl * 132))[q] = v;
    }
    __syncthreads();
    int o = tid & 15;
    int nl = tid >> 4;
    int n = base + nl;
    if (n >= N) return;
    const float4* xr4 = (const float4*)(xtile + nl * 132);
    const float4* wur4 = (const float4*)(wlds + o * 132);
    const float4* wvr4 = (const float4*)(wlds + (16 + o) * 132);
    float au0 = 0.f, au1 = 0.f, au2 = 0.f, au3 = 0.f;
    float av0 = 0.f, av1 = 0.f, av2 = 0.f, av3 = 0.f;
#pragma unroll
    for (int kk = 0; kk < 32; ++kk) {
        float4 xv = xr4[kk];
        float4 wuv = wur4[kk];
        float4 wvv = wvr4[kk];
        au0 = fmaf(xv.x, wuv.x, au0);  av0 = fmaf(xv.x, wvv.x, av0);
        au1 = fmaf(xv.y, wuv.y, au1);  av1 = fmaf(xv.y, wvv.y, av1);
        au2 = fmaf(xv.z, wuv.z, au2);  av2 = fmaf(xv.z, wvv.z, av2);
        au3 = fmaf(xv.w, wuv.w, au3);  av3 = fmaf(xv.w, wvv.w, av3);
    }
    su[n * 16 + o] = ((au0 + au1) + (au2 + au3)) + bu[o];
    sv[n * 16 + o] = (av0 + av1) + (av2 + av3);
}

// ---------------- buildagg: R2 agg structure, but the LDS counting sort now
// keys on (node<<4 | src>>12): within each node's bucket, edges are grouped
// by 4096-row src slab -> all concurrently-resident blocks sweep the 12.8 MB
// xbf table in ASCENDING src order (convoy) -> the per-XCD 4 MB L2 holds the
// sweep window instead of thrashing the whole table (FETCH was ~265 MB from
// cross-XCD re-misses; table is only 12.8 MB).
__global__ __launch_bounds__(256, 8) void buildagg_kernel(
    const ushort* __restrict__ xbf, const float* __restrict__ su,
    const float* __restrict__ sv, const int* __restrict__ gcur,
    const unsigned* __restrict__ pairs, float* __restrict__ out,
    int N, int E, int nr, int cap)
{
    __shared__ ushort srcs[768];              // sorted src ids (cap <= 704)
    __shared__ int offl[33];
    __shared__ int cnt512[512];               // (node<<4|slab) counters -> cursors
    __shared__ int wpart[4];
    __shared__ __align__(16) float ev4[4][512];
    int r = blockIdx.x, t = blockIdx.y, tid = threadIdx.x;
    int m = gcur[t * nr + r];
    if (m > cap) m = cap;                     // safety (never expected)
    const unsigned* p = pairs + ((size_t)t * nr + r) * cap;

    for (int i = tid; i < 512; i += 256) cnt512[i] = 0;
    __syncthreads();
    for (int i = tid; i < m; i += 256) {      // pass 1: histogram on (node,slab)
        unsigned v = p[i];
        int key = ((int)((v >> 16) & (RW - 1)) << 4) | (int)((v & 0xffffu) >> 12);
        atomicAdd(&cnt512[key], 1);
    }
    __syncthreads();
    {                                         // 512-wide exclusive scan, 256 thr
        int a = cnt512[2 * tid], b = cnt512[2 * tid + 1];
        int s = a + b;
        int lane = tid & 63, wid = tid >> 6;
        int incl = s;
#pragma unroll
        for (int d = 1; d < 64; d <<= 1) {
            int o = __shfl(incl, lane - d);
            if (lane >= d) incl += o;
        }
        if (lane == 63) wpart[wid] = incl;
        __syncthreads();
        int bsum = 0;
        for (int w = 0; w < wid; ++w) bsum += wpart[w];
        int excl = bsum + incl - s;
        cnt512[2 * tid] = excl;               // -> scatter cursors
        cnt512[2 * tid + 1] = excl + a;
        if ((tid & 7) == 0) offl[tid >> 3] = excl;   // bucket 2*tid = node*16
        if (tid == 0) offl[32] = m;
    }
    __syncthreads();
    for (int i = tid; i < m; i += 256) {      // pass 2: scatter into LDS bucket
        unsigned v = p[i];
        int key = ((int)((v >> 16) & (RW - 1)) << 4) | (int)((v & 0xffffu) >> 12);
        int pos = atomicAdd(&cnt512[key], 1);
        srcs[pos] = (ushort)(v & 0xffffu);
    }
    __syncthreads();

    // ---- agg: wave w handles local nodes w, w+4, ...
    int wid = tid >> 6, lane = tid & 63;
    int g2 = lane >> 4, q16 = lane & 15;
    int j0 = q16 * 8;                         // 8 dims/lane, heads 0..7 in order
    int eg = lane >> 1;                       // e-phase: edge slot 0..31
    int hh = (lane & 1) * 4;                  // e-phase: head half {0,4}
    float* ev = ev4[wid];
    for (int ln = wid; ln < RW; ln += 4) {
        int n = (r << RSHIFT) + ln;
        if (n >= N) break;
        int beg = offl[ln], end = offl[ln + 1];
        float4 vh4 = *(const float4*)(sv + (size_t)n * 16 + t * 8 + hh);
        float a0 = 0.f, a1 = 0.f, a2 = 0.f, a3 = 0.f;
        float a4 = 0.f, a5 = 0.f, a6 = 0.f, a7 = 0.f;
        float4 l4 = make_float4(0.f, 0.f, 0.f, 0.f);
        for (int cbeg = beg; cbeg < end; cbeg += 64) {
            int cnt = min(end - cbeg, 64);
            int gmax = (cnt + 31) >> 5;
            for (int g = 0; g < gmax; ++g) {  // e-phase: 32 edges x 8 heads/iter
                int e = g * 32 + eg;
                bool valid = e < cnt;
                int sidx = srcs[cbeg + (valid ? e : 0)];
                float4 fu = *(const float4*)(su + (size_t)sidx * 16 + t * 8 + hh);
                float sx = fu.x + vh4.x; sx = (sx >= 0.f) ? sx : NEG_SLOPE * sx;
                float sy = fu.y + vh4.y; sy = (sy >= 0.f) ? sy : NEG_SLOPE * sy;
                float sz = fu.z + vh4.z; sz = (sz >= 0.f) ? sz : NEG_SLOPE * sz;
                float sw = fu.w + vh4.w; sw = (sw >= 0.f) ? sw : NEG_SLOPE * sw;
                float4 ee;
                ee.x = valid ? __expf(sx) : 0.f;
                ee.y = valid ? __expf(sy) : 0.f;
                ee.z = valid ? __expf(sz) : 0.f;
                ee.w = valid ? __expf(sw) : 0.f;
                l4.x += ee.x; l4.y += ee.y; l4.z += ee.z; l4.w += ee.w;
                *(float4*)(ev + e * 8 + hh) = ee;   // contiguous b128, conflict-free
            }
            int quads = (cnt + 3) >> 2;
            for (int i4 = 0; i4 < quads; i4 += 2) {   // acc: 8 edges/iter/wave
                int e0 = (i4 << 2) + g2, e1 = e0 + 4; // e1 <= 63 for all cnt<=64
                int sA = srcs[cbeg + ((e0 < cnt) ? e0 : 0)];
                int sB = srcs[cbeg + ((e1 < cnt) ? e1 : 0)];
                uint4 uA = *(const uint4*)(xbf + (size_t)sA * 128 + j0);
                uint4 uB = *(const uint4*)(xbf + (size_t)sB * 128 + j0);
                float4 pA0 = *(const float4*)(ev + e0 * 8);
                float4 pA1 = *(const float4*)(ev + e0 * 8 + 4);
                float4 pB0 = *(const float4*)(ev + e1 * 8);
                float4 pB1 = *(const float4*)(ev + e1 * 8 + 4);
                a0 = fmaf(bflo(uA.x), pA0.x, a0);
                a1 = fmaf(bfhi(uA.x), pA0.y, a1);
                a2 = fmaf(bflo(uA.y), pA0.z, a2);
                a3 = fmaf(bfhi(uA.y), pA0.w, a3);
                a4 = fmaf(bflo(uA.z), pA1.x, a4);
                a5 = fmaf(bfhi(uA.z), pA1.y, a5);
                a6 = fmaf(bflo(uA.w), pA1.z, a6);
                a7 = fmaf(bfhi(uA.w), pA1.w, a7);
                a0 = fmaf(bflo(uB.x), pB0.x, a0);
                a1 = fmaf(bfhi(uB.x), pB0.y, a1);
                a2 = fmaf(bflo(uB.y), pB0.z, a2);
                a3 = fmaf(bfhi(uB.y), pB0.w, a3);
                a4 = fmaf(bflo(uB.z), pB1.x, a4);
                a5 = fmaf(bfhi(uB.z), pB1.y, a5);
                a6 = fmaf(bflo(uB.w), pB1.z, a6);
                a7 = fmaf(bfhi(uB.w), pB1.w, a7);
            }
        }
        // softmax denom: reduce l4 over 32 edge slots (strides keep lane&1 parity)
        l4.x += __shfl_xor(l4.x, 2);  l4.y += __shfl_xor(l4.y, 2);
        l4.z += __shfl_xor(l4.z, 2);  l4.w += __shfl_xor(l4.w, 2);
        l4.x += __shfl_xor(l4.x, 4);  l4.y += __shfl_xor(l4.y, 4);
        l4.z += __shfl_xor(l4.z, 4);  l4.w += __shfl_xor(l4.w, 4);
        l4.x += __shfl_xor(l4.x, 8);  l4.y += __shfl_xor(l4.y, 8);
        l4.z += __shfl_xor(l4.z, 8);  l4.w += __shfl_xor(l4.w, 8);
        l4.x += __shfl_xor(l4.x, 16); l4.y += __shfl_xor(l4.y, 16);
        l4.z += __shfl_xor(l4.z, 16); l4.w += __shfl_xor(l4.w, 16);
        l4.x += __shfl_xor(l4.x, 32); l4.y += __shfl_xor(l4.y, 32);
        l4.z += __shfl_xor(l4.z, 32); l4.w += __shfl_xor(l4.w, 32);
        float4 invl4;
        invl4.x = (l4.x > 0.f) ? (1.f / l4.x) : 0.f;
        invl4.y = (l4.y > 0.f) ? (1.f / l4.y) : 0.f;
        invl4.z = (l4.z > 0.f) ? (1.f / l4.z) : 0.f;
        invl4.w = (l4.w > 0.f) ? (1.f / l4.w) : 0.f;
        // accumulator reduce across the 4 edge groups
        a0 += __shfl_xor(a0, 16); a0 += __shfl_xor(a0, 32);
        a1 += __shfl_xor(a1, 16); a1 += __shfl_xor(a1, 32);
        a2 += __shfl_xor(a2, 16); a2 += __shfl_xor(a2, 32);
        a3 += __shfl_xor(a3, 16); a3 += __shfl_xor(a3, 32);
        a4 += __shfl_xor(a4, 16); a4 += __shfl_xor(a4, 32);
        a5 += __shfl_xor(a5, 16); a5 += __shfl_xor(a5, 32);
        a6 += __shfl_xor(a6, 16); a6 += __shfl_xor(a6, 32);
        a7 += __shfl_xor(a7, 16); a7 += __shfl_xor(a7, 32);
        // heads 0..3 live on even lanes (lane 0), heads 4..7 on odd (lane 1)
        float ih0 = __shfl(invl4.x, 0);
        float ih1 = __shfl(invl4.y, 0);
        float ih2 = __shfl(invl4.z, 0);
        float ih3 = __shfl(invl4.w, 0);
        float ih4 = __shfl(invl4.x, 1);
        float ih5 = __shfl(invl4.y, 1);
        float ih6 = __shfl(invl4.z, 1);
        float ih7 = __shfl(invl4.w, 1);
        if (g2 == 0) {
            float* op = out + (size_t)n * 384 + 128 + (size_t)t * 128 + j0;
            *(float4*)op       = make_float4(a0 * ih0, a1 * ih1, a2 * ih2, a3 * ih3);
            *(float4*)(op + 4) = make_float4(a4 * ih4, a5 * ih5, a6 * ih6, a7 * ih7);
        }
    }
}

extern "C" void kernel_launch(void* const* d_in, const int* in_sizes, int n_in,
                              void* d_out, int out_size, void* d_ws, size_t ws_size,
                              hipStream_t stream)
{
    const float* x  = (const float*)d_in[0];
    const float* wu = (const float*)d_in[1];
    const float* bu = (const float*)d_in[2];
    const float* wv = (const float*)d_in[3];
    const int* s0 = (const int*)d_in[4];
    const int* d0 = (const int*)d_in[5];
    const int* s1 = (const int*)d_in[6];
    const int* d1 = (const int*)d_in[7];
    float* out = (float*)d_out;
    int N = in_sizes[0] / 128;
    int E = in_sizes[4];

    int nr = ((N - 1) >> RSHIFT) + 1;               // 1563 for N=50000 (<= MAXNR)
    long long mean = (long long)RW * E / N;         // ~512
    int cap = (int)(mean + mean / 4 + 64);          // 704 (>8 sigma margin)

    char* ws = (char*)d_ws;
    size_t o = 0;
    auto alloc = [&](size_t bytes) -> void* {
        void* p = ws + o;
        o = (o + bytes + 255) & ~(size_t)255;
        return p;
    };
    float* su       = (float*)alloc((size_t)N * 16 * 4);
    float* sv       = (float*)alloc((size_t)N * 16 * 4);
    int* gcur       = (int*)alloc((size_t)2 * nr * 4);
    unsigned* pairs = (unsigned*)alloc((size_t)2 * nr * cap * 4);
    ushort* xbf     = (ushort*)alloc((size_t)N * 128 * 2);

    int scoreBlocks = (N + 15) / 16;                // 3125
    int ppset       = (E + CHUNKP - 1) / CHUNKP;    // 98

    hipMemsetAsync(gcur, 0, (size_t)2 * nr * 4, stream);
    mega_kernel<<<scoreBlocks + 2 * ppset, 256, 0, stream>>>(
        x, wu, bu, wv, s0, d0, s1, d1, out, xbf, su, sv,
        gcur, pairs, N, E, nr, cap, scoreBlocks, ppset);
    buildagg_kernel<<<dim3(nr, 2), 256, 0, stream>>>(
        xbf, su, sv, gcur, pairs, out, N, E, nr, cap);
}

// Round 7
// 253.025 us; speedup vs baseline: 1.0662x; 1.0662x over previous
//
#include <hip/hip_runtime.h>

#define NEG_SLOPE 0.2f
#define RSHIFT 5       // range width 32 dst nodes -> LDS-resident counting sort
#define RW     32
#define MAXNR  1600    // supports N <= 51200
#define CHUNKP 8192    // edges per partition block

__device__ __forceinline__ ushort f2bf(float f) {
    union { float f; unsigned u; } c; c.f = f;
    unsigned u = c.u;
    return (ushort)((u + 0x7fffu + ((u >> 16) & 1u)) >> 16);   // RNE
}
__device__ __forceinline__ float bflo(unsigned u) { return __uint_as_float(u << 16); }
__device__ __forceinline__ float bfhi(unsigned u) { return __uint_as_float(u & 0xffff0000u); }

// ---------------- mega: partition FIRST (overlaps under scores), then fused
// scores+copy+convert. 32 nodes per score block (halves redundant weight
// staging: 3125->1563 blocks x 16KB). Weight rows padded to 132 floats.
__global__ __launch_bounds__(256) void mega_kernel(
    const float* __restrict__ x, const float* __restrict__ wu,
    const float* __restrict__ bu, const float* __restrict__ wv,
    const int* __restrict__ s0, const int* __restrict__ d0,
    const int* __restrict__ s1, const int* __restrict__ d1,
    float* __restrict__ out, ushort* __restrict__ xbf,
    float* __restrict__ su, float* __restrict__ sv,
    int* __restrict__ gcur, unsigned* __restrict__ pairs,
    int N, int E, int nr, int cap, int scoreBlocks, int ppset)
{
    __shared__ __align__(16) float smemf[32 * 132 + 32 * 132];  // 33.8 KB
    int* smi = (int*)smemf;                   // role C alias (needs 3*MAXNR=4800)
    float* wlds = smemf;                      // weights 32x132 (pad 132: f4-aligned)
    float* xtile = smemf + 32 * 132;          // x rows  32x132
    int tid = threadIdx.x;
    int bid = blockIdx.x;

    if (bid < 2 * ppset) {                    // ---- role C: partition edges
        int pb = bid;
        int t = pb / ppset, c = pb % ppset;
        const int* ss = t ? s1 : s0;
        const int* dd = t ? d1 : d0;
        int beg = c * CHUNKP, end = min(E, beg + CHUNKP);
        int* lcnt = smi; int* gb = smi + MAXNR; int* lrun = smi + 2 * MAXNR;
        for (int i = tid; i < nr; i += 256) lcnt[i] = 0;
        __syncthreads();
        for (int e = beg + tid; e < end; e += 256)
            atomicAdd(&lcnt[dd[e] >> RSHIFT], 1);
        __syncthreads();
        for (int i = tid; i < nr; i += 256) {
            gb[i] = atomicAdd(&gcur[t * nr + i], lcnt[i]);
            lrun[i] = 0;
        }
        __syncthreads();
        unsigned* pt = pairs + (size_t)t * nr * cap;
        for (int e = beg + tid; e < end; e += 256) {
            int dst = dd[e], src = ss[e];
            int rr = dst >> RSHIFT;
            int pos = atomicAdd(&lrun[rr], 1);
            pt[(size_t)rr * cap + gb[rr] + pos] = ((unsigned)dst << 16) | (unsigned)src;
        }
        return;
    }
    // ---- role B (fused): stage 32 rows + emit out/xbf, then scores from LDS
    int nb = bid - 2 * ppset;                 // 0..scoreBlocks-1
    int base = nb * 32;
    for (int i = tid; i < 1024; i += 256) {   // weights via float4: 32 rows x 32 f4
        int o = i >> 5, k4 = i & 31;
        float4 w = (o < 16) ? ((const float4*)wu)[i] : ((const float4*)wv)[i - 512];
        *(float4*)(wlds + o * 132 + k4 * 4) = w;
    }
    for (int i2 = tid; i2 < 1024; i2 += 256) {// 32 rows x 32 float4
        int I = nb * 1024 + i2;               // global float4 index into x
        int nl = i2 >> 5, q = i2 & 31;
        int n = base + nl;
        float4 v = make_float4(0.f, 0.f, 0.f, 0.f);
        if (n < N) {
            v = ((const float4*)x)[I];
            ((float4*)out)[(size_t)n * 96 + q] = v;
            ushort4 b;
            b.x = f2bf(v.x); b.y = f2bf(v.y); b.z = f2bf(v.z); b.w = f2bf(v.w);
            *(ushort4*)(xbf + (size_t)I * 4) = b;
        }
        ((float4*)(xtile + nl * 132))[q] = v;
    }
    __syncthreads();
    int o = tid & 15;
    const float4* wur4 = (const float4*)(wlds + o * 132);
    const float4* wvr4 = (const float4*)(wlds + (16 + o) * 132);
#pragma unroll
    for (int half = 0; half < 2; ++half) {
        int nl = (tid >> 4) + half * 16;
        int n = base + nl;
        if (n >= N) continue;
        const float4* xr4 = (const float4*)(xtile + nl * 132);
        float au0 = 0.f, au1 = 0.f, au2 = 0.f, au3 = 0.f;
        float av0 = 0.f, av1 = 0.f, av2 = 0.f, av3 = 0.f;
#pragma unroll
        for (int kk = 0; kk < 32; ++kk) {
            float4 xv = xr4[kk];
            float4 wuv = wur4[kk];
            float4 wvv = wvr4[kk];
            au0 = fmaf(xv.x, wuv.x, au0);  av0 = fmaf(xv.x, wvv.x, av0);
            au1 = fmaf(xv.y, wuv.y, au1);  av1 = fmaf(xv.y, wvv.y, av1);
            au2 = fmaf(xv.z, wuv.z, au2);  av2 = fmaf(xv.z, wvv.z, av2);
            au3 = fmaf(xv.w, wuv.w, au3);  av3 = fmaf(xv.w, wvv.w, av3);
        }
        su[n * 16 + o] = ((au0 + au1) + (au2 + au3)) + bu[o];
        sv[n * 16 + o] = (av0 + av1) + (av2 + av3);
    }
}

// ---------------- buildagg: R2 structure (32-bucket sort, proven 82 us) but
// 4-deep acc gathering under __launch_bounds__(256,6): 85-VGPR budget so the
// 4 in-flight uint4 rows fit WITHOUT the scratch spill that hit the 64-cap
// (R3). Trades 8->6 waves/EU for 2x in-flight gathers (net MLP +50%).
__global__ __launch_bounds__(256, 6) void buildagg_kernel(
    const ushort* __restrict__ xbf, const float* __restrict__ su,
    const float* __restrict__ sv, const int* __restrict__ gcur,
    const unsigned* __restrict__ pairs, float* __restrict__ out,
    int N, int E, int nr, int cap)
{
    __shared__ ushort srcs[768];              // sorted src ids (cap <= 704)
    __shared__ int offl[33];
    __shared__ int cursor[32];
    __shared__ __align__(16) float ev4[4][512];
    int r = blockIdx.x, t = blockIdx.y, tid = threadIdx.x;
    int m = gcur[t * nr + r];
    if (m > cap) m = cap;                     // safety (never expected)
    const unsigned* p = pairs + ((size_t)t * nr + r) * cap;

    if (tid < 32) cursor[tid] = 0;
    __syncthreads();
    for (int i = tid; i < m; i += 256)        // pass 1: histogram (local node id)
        atomicAdd(&cursor[(p[i] >> 16) & (RW - 1)], 1);
    __syncthreads();
    if (tid < 32) {                           // 32-wide shfl scan -> offsets
        int v = cursor[tid];
        int incl = v;
#pragma unroll
        for (int d = 1; d < 32; d <<= 1) {
            int o = __shfl(incl, tid - d);
            if (tid >= d) incl += o;
        }
        offl[tid + 1] = incl;
        if (tid == 0) offl[0] = 0;
        cursor[tid] = incl - v;               // exclusive -> scatter cursor
    }
    __syncthreads();
    for (int i = tid; i < m; i += 256) {      // pass 2: scatter into LDS bucket
        unsigned v = p[i];
        int pos = atomicAdd(&cursor[(v >> 16) & (RW - 1)], 1);
        srcs[pos] = (ushort)(v & 0xffffu);
    }
    __syncthreads();

    // ---- agg: wave w handles local nodes w, w+4, ...
    int wid = tid >> 6, lane = tid & 63;
    int g2 = lane >> 4, q16 = lane & 15;
    int j0 = q16 * 8;                         // 8 dims/lane, heads 0..7 in order
    int eg = lane >> 1;                       // e-phase: edge slot 0..31
    int hh = (lane & 1) * 4;                  // e-phase: head half {0,4}
    float* ev = ev4[wid];
    for (int ln = wid; ln < RW; ln += 4) {
        int n = (r << RSHIFT) + ln;
        if (n >= N) break;
        int beg = offl[ln], end = offl[ln + 1];
        float4 vh4 = *(const float4*)(sv + (size_t)n * 16 + t * 8 + hh);
        float a0 = 0.f, a1 = 0.f, a2 = 0.f, a3 = 0.f;
        float a4 = 0.f, a5 = 0.f, a6 = 0.f, a7 = 0.f;
        float4 l4 = make_float4(0.f, 0.f, 0.f, 0.f);
        for (int cbeg = beg; cbeg < end; cbeg += 64) {
            int cnt = min(end - cbeg, 64);
            int gmax = (cnt + 31) >> 5;
            for (int g = 0; g < gmax; ++g) {  // e-phase: 32 edges x 8 heads/iter
                int e = g * 32 + eg;
                bool valid = e < cnt;
                int sidx = srcs[cbeg + (valid ? e : 0)];
                float4 fu = *(const float4*)(su + (size_t)sidx * 16 + t * 8 + hh);
                float sx = fu.x + vh4.x; sx = (sx >= 0.f) ? sx : NEG_SLOPE * sx;
                float sy = fu.y + vh4.y; sy = (sy >= 0.f) ? sy : NEG_SLOPE * sy;
                float sz = fu.z + vh4.z; sz = (sz >= 0.f) ? sz : NEG_SLOPE * sz;
                float sw = fu.w + vh4.w; sw = (sw >= 0.f) ? sw : NEG_SLOPE * sw;
                float4 ee;
                ee.x = valid ? __expf(sx) : 0.f;
                ee.y = valid ? __expf(sy) : 0.f;
                ee.z = valid ? __expf(sz) : 0.f;
                ee.w = valid ? __expf(sw) : 0.f;
                l4.x += ee.x; l4.y += ee.y; l4.z += ee.z; l4.w += ee.w;
                *(float4*)(ev + e * 8 + hh) = ee;   // contiguous b128, conflict-free
            }
            int quads = (cnt + 3) >> 2;
            for (int i4 = 0; i4 < quads; i4 += 4) {   // acc: 16 edges/iter/wave
                int e0 = (i4 << 2) + g2;              // probes <= 32*gmax-1 (checked)
                int e1 = e0 + 4, e2 = e0 + 8, e3 = e0 + 12;
                int sA = srcs[cbeg + ((e0 < cnt) ? e0 : 0)];
                int sB = srcs[cbeg + ((e1 < cnt) ? e1 : 0)];
                int sC = srcs[cbeg + ((e2 < cnt) ? e2 : 0)];
                int sD = srcs[cbeg + ((e3 < cnt) ? e3 : 0)];
                uint4 uA = *(const uint4*)(xbf + (size_t)sA * 128 + j0);
                uint4 uB = *(const uint4*)(xbf + (size_t)sB * 128 + j0);
                uint4 uC = *(const uint4*)(xbf + (size_t)sC * 128 + j0);
                uint4 uD = *(const uint4*)(xbf + (size_t)sD * 128 + j0);
                {
                    float4 p0 = *(const float4*)(ev + e0 * 8);
                    float4 p1 = *(const float4*)(ev + e0 * 8 + 4);
                    a0 = fmaf(bflo(uA.x), p0.x, a0);
                    a1 = fmaf(bfhi(uA.x), p0.y, a1);
                    a2 = fmaf(bflo(uA.y), p0.z, a2);
                    a3 = fmaf(bfhi(uA.y), p0.w, a3);
                    a4 = fmaf(bflo(uA.z), p1.x, a4);
                    a5 = fmaf(bfhi(uA.z), p1.y, a5);
                    a6 = fmaf(bflo(uA.w), p1.z, a6);
                    a7 = fmaf(bfhi(uA.w), p1.w, a7);
                }
                {
                    float4 p0 = *(const float4*)(ev + e1 * 8);
                    float4 p1 = *(const float4*)(ev + e1 * 8 + 4);
                    a0 = fmaf(bflo(uB.x), p0.x, a0);
                    a1 = fmaf(bfhi(uB.x), p0.y, a1);
                    a2 = fmaf(bflo(uB.y), p0.z, a2);
                    a3 = fmaf(bfhi(uB.y), p0.w, a3);
                    a4 = fmaf(bflo(uB.z), p1.x, a4);
                    a5 = fmaf(bfhi(uB.z), p1.y, a5);
                    a6 = fmaf(bflo(uB.w), p1.z, a6);
                    a7 = fmaf(bfhi(uB.w), p1.w, a7);
                }
                {
                    float4 p0 = *(const float4*)(ev + e2 * 8);
                    float4 p1 = *(const float4*)(ev + e2 * 8 + 4);
                    a0 = fmaf(bflo(uC.x), p0.x, a0);
                    a1 = fmaf(bfhi(uC.x), p0.y, a1);
                    a2 = fmaf(bflo(uC.y), p0.z, a2);
                    a3 = fmaf(bfhi(uC.y), p0.w, a3);
                    a4 = fmaf(bflo(uC.z), p1.x, a4);
                    a5 = fmaf(bfhi(uC.z), p1.y, a5);
                    a6 = fmaf(bflo(uC.w), p1.z, a6);
                    a7 = fmaf(bfhi(uC.w), p1.w, a7);
                }
                {
                    float4 p0 = *(const float4*)(ev + e3 * 8);
                    float4 p1 = *(const float4*)(ev + e3 * 8 + 4);
                    a0 = fmaf(bflo(uD.x), p0.x, a0);
                    a1 = fmaf(bfhi(uD.x), p0.y, a1);
                    a2 = fmaf(bflo(uD.y), p0.z, a2);
                    a3 = fmaf(bfhi(uD.y), p0.w, a3);
                    a4 = fmaf(bflo(uD.z), p1.x, a4);
                    a5 = fmaf(bfhi(uD.z), p1.y, a5);
                    a6 = fmaf(bflo(uD.w), p1.z, a6);
                    a7 = fmaf(bfhi(uD.w), p1.w, a7);
                }
            }
        }
        // softmax denom: reduce l4 over 32 edge slots (strides keep lane&1 parity)
        l4.x += __shfl_xor(l4.x, 2);  l4.y += __shfl_xor(l4.y, 2);
        l4.z += __shfl_xor(l4.z, 2);  l4.w += __shfl_xor(l4.w, 2);
        l4.x += __shfl_xor(l4.x, 4);  l4.y += __shfl_xor(l4.y, 4);
        l4.z += __shfl_xor(l4.z, 4);  l4.w += __shfl_xor(l4.w, 4);
        l4.x += __shfl_xor(l4.x, 8);  l4.y += __shfl_xor(l4.y, 8);
        l4.z += __shfl_xor(l4.z, 8);  l4.w += __shfl_xor(l4.w, 8);
        l4.x += __shfl_xor(l4.x, 16); l4.y += __shfl_xor(l4.y, 16);
        l4.z += __shfl_xor(l4.z, 16); l4.w += __shfl_xor(l4.w, 16);
        l4.x += __shfl_xor(l4.x, 32); l4.y += __shfl_xor(l4.y, 32);
        l4.z += __shfl_xor(l4.z, 32); l4.w += __shfl_xor(l4.w, 32);
        float4 invl4;
        invl4.x = (l4.x > 0.f) ? (1.f / l4.x) : 0.f;
        invl4.y = (l4.y > 0.f) ? (1.f / l4.y) : 0.f;
        invl4.z = (l4.z > 0.f) ? (1.f / l4.z) : 0.f;
        invl4.w = (l4.w > 0.f) ? (1.f / l4.w) : 0.f;
        // accumulator reduce across the 4 edge groups
        a0 += __shfl_xor(a0, 16); a0 += __shfl_xor(a0, 32);
        a1 += __shfl_xor(a1, 16); a1 += __shfl_xor(a1, 32);
        a2 += __shfl_xor(a2, 16); a2 += __shfl_xor(a2, 32);
        a3 += __shfl_xor(a3, 16); a3 += __shfl_xor(a3, 32);
        a4 += __shfl_xor(a4, 16); a4 += __shfl_xor(a4, 32);
        a5 += __shfl_xor(a5, 16); a5 += __shfl_xor(a5, 32);
        a6 += __shfl_xor(a6, 16); a6 += __shfl_xor(a6, 32);
        a7 += __shfl_xor(a7, 16); a7 += __shfl_xor(a7, 32);
        // heads 0..3 live on even lanes (lane 0), heads 4..7 on odd (lane 1)
        float ih0 = __shfl(invl4.x, 0);
        float ih1 = __shfl(invl4.y, 0);
        float ih2 = __shfl(invl4.z, 0);
        float ih3 = __shfl(invl4.w, 0);
        float ih4 = __shfl(invl4.x, 1);
        float ih5 = __shfl(invl4.y, 1);
        float ih6 = __shfl(invl4.z, 1);
        float ih7 = __shfl(invl4.w, 1);
        if (g2 == 0) {
            float* op = out + (size_t)n * 384 + 128 + (size_t)t * 128 + j0;
            *(float4*)op       = make_float4(a0 * ih0, a1 * ih1, a2 * ih2, a3 * ih3);
            *(float4*)(op + 4) = make_float4(a4 * ih4, a5 * ih5, a6 * ih6, a7 * ih7);
        }
    }
}

extern "C" void kernel_launch(void* const* d_in, const int* in_sizes, int n_in,
                              void* d_out, int out_size, void* d_ws, size_t ws_size,
                              hipStream_t stream)
{
    const float* x  = (const float*)d_in[0];
    const float* wu = (const float*)d_in[1];
    const float* bu = (const float*)d_in[2];
    const float* wv = (const float*)d_in[3];
    const int* s0 = (const int*)d_in[4];
    const int* d0 = (const int*)d_in[5];
    const int* s1 = (const int*)d_in[6];
    const int* d1 = (const int*)d_in[7];
    float* out = (float*)d_out;
    int N = in_sizes[0] / 128;
    int E = in_sizes[4];

    int nr = ((N - 1) >> RSHIFT) + 1;               // 1563 for N=50000 (<= MAXNR)
    long long mean = (long long)RW * E / N;         // ~512
    int cap = (int)(mean + mean / 4 + 64);          // 704 (>8 sigma margin)

    char* ws = (char*)d_ws;
    size_t o = 0;
    auto alloc = [&](size_t bytes) -> void* {
        void* p = ws + o;
        o = (o + bytes + 255) & ~(size_t)255;
        return p;
    };
    float* su       = (float*)alloc((size_t)N * 16 * 4);
    float* sv       = (float*)alloc((size_t)N * 16 * 4);
    int* gcur       = (int*)alloc((size_t)2 * nr * 4);
    unsigned* pairs = (unsigned*)alloc((size_t)2 * nr * cap * 4);
    ushort* xbf     = (ushort*)alloc((size_t)N * 128 * 2);

    int scoreBlocks = (N + 31) / 32;                // 1563
    int ppset       = (E + CHUNKP - 1) / CHUNKP;    // 98

    hipMemsetAsync(gcur, 0, (size_t)2 * nr * 4, stream);
    mega_kernel<<<scoreBlocks + 2 * ppset, 256, 0, stream>>>(
        x, wu, bu, wv, s0, d0, s1, d1, out, xbf, su, sv,
        gcur, pairs, N, E, nr, cap, scoreBlocks, ppset);
    buildagg_kernel<<<dim3(nr, 2), 256, 0, stream>>>(
        xbf, su, sv, gcur, pairs, out, N, E, nr, cap);
}

// Round 8
// 243.711 us; speedup vs baseline: 1.1070x; 1.0382x over previous
//
#include <hip/hip_runtime.h>

#define NEG_SLOPE 0.2f
#define RSHIFT 5       // range width 32 dst nodes -> LDS-resident counting sort
#define RW     32
#define MAXNR  1600    // supports N <= 51200
#define CHUNKP 8192    // edges per partition block

__device__ __forceinline__ ushort f2bf(float f) {
    union { float f; unsigned u; } c; c.f = f;
    unsigned u = c.u;
    return (ushort)((u + 0x7fffu + ((u >> 16) & 1u)) >> 16);   // RNE
}
__device__ __forceinline__ float bflo(unsigned u) { return __uint_as_float(u << 16); }
__device__ __forceinline__ float bfhi(unsigned u) { return __uint_as_float(u & 0xffff0000u); }

// ---------------- mega: partition FIRST (overlaps under scores), then fused
// scores+copy+convert: each score block stages its 16 x-rows in LDS, emits
// out[:, :128] and xbf during staging, computes scores from LDS (x read ONCE).
// su/sv are stored T-MAJOR: su[t][n][8] -- each buildagg block then gathers
// from a 1.6 MB table (L2-resident per XCD) with 100%-useful lines.
__global__ __launch_bounds__(256) void mega_kernel(
    const float* __restrict__ x, const float* __restrict__ wu,
    const float* __restrict__ bu, const float* __restrict__ wv,
    const int* __restrict__ s0, const int* __restrict__ d0,
    const int* __restrict__ s1, const int* __restrict__ d1,
    float* __restrict__ out, ushort* __restrict__ xbf,
    float* __restrict__ su, float* __restrict__ sv,
    int* __restrict__ gcur, unsigned* __restrict__ pairs,
    int N, int E, int nr, int cap, int scoreBlocks, int ppset)
{
    __shared__ __align__(16) float smemf[32 * 129 + 16 * 132];  // 24.96 KB
    int* smi = (int*)smemf;                   // role C alias (needs 3*MAXNR=4800)
    float* wlds = smemf;                      // weights 32x129
    float* xtile = smemf + 32 * 129;          // x rows  16x132 (pad -> 2-way)
    int tid = threadIdx.x;
    int bid = blockIdx.x;

    if (bid < 2 * ppset) {                    // ---- role C: partition edges
        int pb = bid;
        int t = pb / ppset, c = pb % ppset;
        const int* ss = t ? s1 : s0;
        const int* dd = t ? d1 : d0;
        int beg = c * CHUNKP, end = min(E, beg + CHUNKP);
        int* lcnt = smi; int* gb = smi + MAXNR; int* lrun = smi + 2 * MAXNR;
        for (int i = tid; i < nr; i += 256) lcnt[i] = 0;
        __syncthreads();
        for (int e = beg + tid; e < end; e += 256)
            atomicAdd(&lcnt[dd[e] >> RSHIFT], 1);
        __syncthreads();
        for (int i = tid; i < nr; i += 256) {
            gb[i] = atomicAdd(&gcur[t * nr + i], lcnt[i]);
            lrun[i] = 0;
        }
        __syncthreads();
        unsigned* pt = pairs + (size_t)t * nr * cap;
        for (int e = beg + tid; e < end; e += 256) {
            int dst = dd[e], src = ss[e];
            int rr = dst >> RSHIFT;
            int pos = atomicAdd(&lrun[rr], 1);
            pt[(size_t)rr * cap + gb[rr] + pos] = ((unsigned)dst << 16) | (unsigned)src;
        }
        return;
    }
    // ---- role B (fused): stage 16 rows + emit out/xbf, then scores from LDS
    int nb = bid - 2 * ppset;                 // 0..scoreBlocks-1
    int base = nb * 16;
    for (int i = tid; i < 4096; i += 256) {
        int o = i >> 7, k = i & 127;
        wlds[o * 129 + k] = (o < 16) ? wu[i] : wv[i - 2048];
    }
    for (int i2 = tid; i2 < 512; i2 += 256) { // 16 rows x 32 float4
        int I = nb * 512 + i2;                // global float4 index into x
        int nl = i2 >> 5, q = i2 & 31;
        int n = base + nl;
        float4 v = make_float4(0.f, 0.f, 0.f, 0.f);
        if (n < N) {
            v = ((const float4*)x)[I];
            ((float4*)out)[(size_t)n * 96 + q] = v;
            ushort4 b;
            b.x = f2bf(v.x); b.y = f2bf(v.y); b.z = f2bf(v.z); b.w = f2bf(v.w);
            *(ushort4*)(xbf + (size_t)I * 4) = b;
        }
        ((float4*)(xtile + nl * 132))[q] = v;
    }
    __syncthreads();
    int o = tid & 15;
    int nl = tid >> 4;
    int n = base + nl;
    if (n >= N) return;
    const float4* xr4 = (const float4*)(xtile + nl * 132);
    const float* wur = wlds + o * 129;
    const float* wvr = wlds + (16 + o) * 129;
    float au = 0.f, av = 0.f;
#pragma unroll
    for (int kk = 0; kk < 32; ++kk) {
        float4 xv = xr4[kk];
        int k = kk * 4;
        au = fmaf(xv.x, wur[k],     au);  av = fmaf(xv.x, wvr[k],     av);
        au = fmaf(xv.y, wur[k + 1], au);  av = fmaf(xv.y, wvr[k + 1], av);
        au = fmaf(xv.z, wur[k + 2], au);  av = fmaf(xv.z, wvr[k + 2], av);
        au = fmaf(xv.w, wur[k + 3], au);  av = fmaf(xv.w, wvr[k + 3], av);
    }
    // t-major split store: o<8 -> t=0 table, o>=8 -> t=1 table
    float resu = au + bu[o];
    float resv = av;
    size_t toff = (o < 8) ? 0 : (size_t)N * 8;
    int ho = o & 7;
    su[toff + (size_t)n * 8 + ho] = resu;
    sv[toff + (size_t)n * 8 + ho] = resv;
}

// ---------------- buildagg: R2 structure (proven best). LDS counting-sort of
// the range's ~512 edges (pairs staged ONCE into LDS, aliasing ev4), then
// per-node single-pass softmax + gather-aggregate. E-phase: 32 edges/iter via
// float4 su gathers from the t-sliced 1.6 MB su table. Acc: 2 x 16B in flight.
__global__ __launch_bounds__(256, 8) void buildagg_kernel(
    const ushort* __restrict__ xbf, const float* __restrict__ su,
    const float* __restrict__ sv, const int* __restrict__ gcur,
    const unsigned* __restrict__ pairs, float* __restrict__ out,
    int N, int E, int nr, int cap)
{
    __shared__ ushort srcs[768];              // sorted src ids (cap <= 704)
    __shared__ int offl[33];
    __shared__ int cursor[32];
    __shared__ __align__(16) float ev4[4][512];   // aliased as pairs-stage below
    int r = blockIdx.x, t = blockIdx.y, tid = threadIdx.x;
    int m = gcur[t * nr + r];
    if (m > cap) m = cap;                     // safety (never expected)
    const unsigned* p = pairs + ((size_t)t * nr + r) * cap;
    const float* sut = su + (size_t)t * N * 8;
    const float* svt = sv + (size_t)t * N * 8;

    unsigned* pl = (unsigned*)ev4;            // 8 KB >= cap*4 (2816 B)
    for (int i = tid; i < m; i += 256)        // stage pairs once (coalesced)
        pl[i] = p[i];
    if (tid < 32) cursor[tid] = 0;
    __syncthreads();
    for (int i = tid; i < m; i += 256)        // pass 1: histogram (local node id)
        atomicAdd(&cursor[(pl[i] >> 16) & (RW - 1)], 1);
    __syncthreads();
    if (tid < 32) {                           // 32-wide shfl scan -> offsets
        int v = cursor[tid];
        int incl = v;
#pragma unroll
        for (int d = 1; d < 32; d <<= 1) {
            int o = __shfl(incl, tid - d);
            if (tid >= d) incl += o;
        }
        offl[tid + 1] = incl;
        if (tid == 0) offl[0] = 0;
        cursor[tid] = incl - v;               // exclusive -> scatter cursor
    }
    __syncthreads();
    for (int i = tid; i < m; i += 256) {      // pass 2: scatter into LDS bucket
        unsigned v = pl[i];
        int pos = atomicAdd(&cursor[(v >> 16) & (RW - 1)], 1);
        srcs[pos] = (ushort)(v & 0xffffu);
    }
    __syncthreads();                          // ev4 free again after this point

    // ---- agg: wave w handles local nodes w, w+4, ...
    int wid = tid >> 6, lane = tid & 63;
    int g2 = lane >> 4, q16 = lane & 15;
    int j0 = q16 * 8;                         // 8 dims/lane, heads 0..7 in order
    int eg = lane >> 1;                       // e-phase: edge slot 0..31
    int hh = (lane & 1) * 4;                  // e-phase: head half {0,4}
    float* ev = ev4[wid];
    for (int ln = wid; ln < RW; ln += 4) {
        int n = (r << RSHIFT) + ln;
        if (n >= N) break;
        int beg = offl[ln], end = offl[ln + 1];
        float4 vh4 = *(const float4*)(svt + (size_t)n * 8 + hh);
        float a0 = 0.f, a1 = 0.f, a2 = 0.f, a3 = 0.f;
        float a4 = 0.f, a5 = 0.f, a6 = 0.f, a7 = 0.f;
        float4 l4 = make_float4(0.f, 0.f, 0.f, 0.f);
        for (int cbeg = beg; cbeg < end; cbeg += 64) {
            int cnt = min(end - cbeg, 64);
            int gmax = (cnt + 31) >> 5;
            for (int g = 0; g < gmax; ++g) {  // e-phase: 32 edges x 8 heads/iter
                int e = g * 32 + eg;
                bool valid = e < cnt;
                int sidx = srcs[cbeg + (valid ? e : 0)];
                float4 fu = *(const float4*)(sut + (size_t)sidx * 8 + hh);
                float sx = fu.x + vh4.x; sx = (sx >= 0.f) ? sx : NEG_SLOPE * sx;
                float sy = fu.y + vh4.y; sy = (sy >= 0.f) ? sy : NEG_SLOPE * sy;
                float sz = fu.z + vh4.z; sz = (sz >= 0.f) ? sz : NEG_SLOPE * sz;
                float sw = fu.w + vh4.w; sw = (sw >= 0.f) ? sw : NEG_SLOPE * sw;
                float4 ee;
                ee.x = valid ? __expf(sx) : 0.f;
                ee.y = valid ? __expf(sy) : 0.f;
                ee.z = valid ? __expf(sz) : 0.f;
                ee.w = valid ? __expf(sw) : 0.f;
                l4.x += ee.x; l4.y += ee.y; l4.z += ee.z; l4.w += ee.w;
                *(float4*)(ev + e * 8 + hh) = ee;   // contiguous b128, conflict-free
            }
            int quads = (cnt + 3) >> 2;
            for (int i4 = 0; i4 < quads; i4 += 2) {   // acc: 8 edges/iter/wave
                int e0 = (i4 << 2) + g2, e1 = e0 + 4; // e1 <= 63 for all cnt<=64
                int sA = srcs[cbeg + ((e0 < cnt) ? e0 : 0)];
                int sB = srcs[cbeg + ((e1 < cnt) ? e1 : 0)];
                uint4 uA = *(const uint4*)(xbf + (size_t)sA * 128 + j0);
                uint4 uB = *(const uint4*)(xbf + (size_t)sB * 128 + j0);
                float4 pA0 = *(const float4*)(ev + e0 * 8);
                float4 pA1 = *(const float4*)(ev + e0 * 8 + 4);
                float4 pB0 = *(const float4*)(ev + e1 * 8);
                float4 pB1 = *(const float4*)(ev + e1 * 8 + 4);
                a0 = fmaf(bflo(uA.x), pA0.x, a0);
                a1 = fmaf(bfhi(uA.x), pA0.y, a1);
                a2 = fmaf(bflo(uA.y), pA0.z, a2);
                a3 = fmaf(bfhi(uA.y), pA0.w, a3);
                a4 = fmaf(bflo(uA.z), pA1.x, a4);
                a5 = fmaf(bfhi(uA.z), pA1.y, a5);
                a6 = fmaf(bflo(uA.w), pA1.z, a6);
                a7 = fmaf(bfhi(uA.w), pA1.w, a7);
                a0 = fmaf(bflo(uB.x), pB0.x, a0);
                a1 = fmaf(bfhi(uB.x), pB0.y, a1);
                a2 = fmaf(bflo(uB.y), pB0.z, a2);
                a3 = fmaf(bfhi(uB.y), pB0.w, a3);
                a4 = fmaf(bflo(uB.z), pB1.x, a4);
                a5 = fmaf(bfhi(uB.z), pB1.y, a5);
                a6 = fmaf(bflo(uB.w), pB1.z, a6);
                a7 = fmaf(bfhi(uB.w), pB1.w, a7);
            }
        }
        // softmax denom: reduce l4 over 32 edge slots (strides keep lane&1 parity)
        l4.x += __shfl_xor(l4.x, 2);  l4.y += __shfl_xor(l4.y, 2);
        l4.z += __shfl_xor(l4.z, 2);  l4.w += __shfl_xor(l4.w, 2);
        l4.x += __shfl_xor(l4.x, 4);  l4.y += __shfl_xor(l4.y, 4);
        l4.z += __shfl_xor(l4.z, 4);  l4.w += __shfl_xor(l4.w, 4);
        l4.x += __shfl_xor(l4.x, 8);  l4.y += __shfl_xor(l4.y, 8);
        l4.z += __shfl_xor(l4.z, 8);  l4.w += __shfl_xor(l4.w, 8);
        l4.x += __shfl_xor(l4.x, 16); l4.y += __shfl_xor(l4.y, 16);
        l4.z += __shfl_xor(l4.z, 16); l4.w += __shfl_xor(l4.w, 16);
        l4.x += __shfl_xor(l4.x, 32); l4.y += __shfl_xor(l4.y, 32);
        l4.z += __shfl_xor(l4.z, 32); l4.w += __shfl_xor(l4.w, 32);
        float4 invl4;
        invl4.x = (l4.x > 0.f) ? (1.f / l4.x) : 0.f;
        invl4.y = (l4.y > 0.f) ? (1.f / l4.y) : 0.f;
        invl4.z = (l4.z > 0.f) ? (1.f / l4.z) : 0.f;
        invl4.w = (l4.w > 0.f) ? (1.f / l4.w) : 0.f;
        // accumulator reduce across the 4 edge groups
        a0 += __shfl_xor(a0, 16); a0 += __shfl_xor(a0, 32);
        a1 += __shfl_xor(a1, 16); a1 += __shfl_xor(a1, 32);
        a2 += __shfl_xor(a2, 16); a2 += __shfl_xor(a2, 32);
        a3 += __shfl_xor(a3, 16); a3 += __shfl_xor(a3, 32);
        a4 += __shfl_xor(a4, 16); a4 += __shfl_xor(a4, 32);
        a5 += __shfl_xor(a5, 16); a5 += __shfl_xor(a5, 32);
        a6 += __shfl_xor(a6, 16); a6 += __shfl_xor(a6, 32);
        a7 += __shfl_xor(a7, 16); a7 += __shfl_xor(a7, 32);
        // heads 0..3 live on even lanes (lane 0), heads 4..7 on odd (lane 1)
        float ih0 = __shfl(invl4.x, 0);
        float ih1 = __shfl(invl4.y, 0);
        float ih2 = __shfl(invl4.z, 0);
        float ih3 = __shfl(invl4.w, 0);
        float ih4 = __shfl(invl4.x, 1);
        float ih5 = __shfl(invl4.y, 1);
        float ih6 = __shfl(invl4.z, 1);
        float ih7 = __shfl(invl4.w, 1);
        if (g2 == 0) {
            float* op = out + (size_t)n * 384 + 128 + (size_t)t * 128 + j0;
            *(float4*)op       = make_float4(a0 * ih0, a1 * ih1, a2 * ih2, a3 * ih3);
            *(float4*)(op + 4) = make_float4(a4 * ih4, a5 * ih5, a6 * ih6, a7 * ih7);
        }
    }
}

extern "C" void kernel_launch(void* const* d_in, const int* in_sizes, int n_in,
                              void* d_out, int out_size, void* d_ws, size_t ws_size,
                              hipStream_t stream)
{
    const float* x  = (const float*)d_in[0];
    const float* wu = (const float*)d_in[1];
    const float* bu = (const float*)d_in[2];
    const float* wv = (const float*)d_in[3];
    const int* s0 = (const int*)d_in[4];
    const int* d0 = (const int*)d_in[5];
    const int* s1 = (const int*)d_in[6];
    const int* d1 = (const int*)d_in[7];
    float* out = (float*)d_out;
    int N = in_sizes[0] / 128;
    int E = in_sizes[4];

    int nr = ((N - 1) >> RSHIFT) + 1;               // 1563 for N=50000 (<= MAXNR)
    long long mean = (long long)RW * E / N;         // ~512
    int cap = (int)(mean + mean / 4 + 64);          // 704 (>8 sigma margin)

    char* ws = (char*)d_ws;
    size_t o = 0;
    auto alloc = [&](size_t bytes) -> void* {
        void* p = ws + o;
        o = (o + bytes + 255) & ~(size_t)255;
        return p;
    };
    float* su       = (float*)alloc((size_t)N * 16 * 4);   // [2][N][8] t-major
    float* sv       = (float*)alloc((size_t)N * 16 * 4);   // [2][N][8] t-major
    int* gcur       = (int*)alloc((size_t)2 * nr * 4);
    unsigned* pairs = (unsigned*)alloc((size_t)2 * nr * cap * 4);
    ushort* xbf     = (ushort*)alloc((size_t)N * 128 * 2);

    int scoreBlocks = (N + 15) / 16;                // 3125
    int ppset       = (E + CHUNKP - 1) / CHUNKP;    // 98

    hipMemsetAsync(gcur, 0, (size_t)2 * nr * 4, stream);
    mega_kernel<<<scoreBlocks + 2 * ppset, 256, 0, stream>>>(
        x, wu, bu, wv, s0, d0, s1, d1, out, xbf, su, sv,
        gcur, pairs, N, E, nr, cap, scoreBlocks, ppset);
    buildagg_kernel<<<dim3(nr, 2), 256, 0, stream>>>(
        xbf, su, sv, gcur, pairs, out, N, E, nr, cap);
}